// Round 2
// baseline (3186.492 us; speedup 1.0000x reference)
//
#include <hip/hip_runtime.h>
#include <math.h>

#define BB   2
#define SS   4096
#define DD   512
#define HH   8
#define HDIM 64

// ---------------------------------------------------------------------------
// Kernel 1: QKV projection.  x:(B*S,512) @ w_qkv:(512,1536) + b_qkv,
// scattered to Q/K/V buffers in (B,H,S,64) layout.
// grid (128 m-tiles, 24 n-tiles), 256 threads, 64x64 tile, 4x4 micro.
// ---------------------------------------------------------------------------
__global__ __launch_bounds__(256)
void qkv_gemm(const float* __restrict__ x, const float* __restrict__ w,
              const float* __restrict__ bias,
              float* __restrict__ Qb, float* __restrict__ Kb, float* __restrict__ Vb)
{
    __shared__ float As[64][20];   // pad 20: rows 80B (16B aligned), 2-way max
    __shared__ float Bs[16][64];
    const int tid = threadIdx.x;
    const int ty = tid >> 4, tx = tid & 15;
    const int m0 = blockIdx.x * 64;
    const int n0 = blockIdx.y * 64;
    const int N  = 3 * DD;

    float c[4][4] = {};

    for (int k0 = 0; k0 < DD; k0 += 16) {
        {
            const int r  = tid >> 2;
            const int c4 = (tid & 3) * 4;
            *(float4*)&As[r][c4] =
                *(const float4*)&x[(size_t)(m0 + r) * DD + k0 + c4];
            const int br  = tid >> 4;
            const int bc4 = (tid & 15) * 4;
            *(float4*)&Bs[br][bc4] =
                *(const float4*)&w[(size_t)(k0 + br) * N + n0 + bc4];
        }
        __syncthreads();
        #pragma unroll
        for (int kk0 = 0; kk0 < 16; kk0 += 4) {
            float4 a4[4];
            #pragma unroll
            for (int i = 0; i < 4; ++i) a4[i] = *(const float4*)&As[ty + 16*i][kk0];
            #pragma unroll
            for (int w4 = 0; w4 < 4; ++w4) {
                float bv[4];
                #pragma unroll
                for (int j = 0; j < 4; ++j) bv[j] = Bs[kk0 + w4][tx + 16*j];
                #pragma unroll
                for (int i = 0; i < 4; ++i) {
                    const float av = ((const float*)&a4[i])[w4];
                    #pragma unroll
                    for (int j = 0; j < 4; ++j) c[i][j] = fmaf(av, bv[j], c[i][j]);
                }
            }
        }
        __syncthreads();
    }

    // scatter epilogue: block's 64 cols are one (head, kind) chunk (192 = 3*64)
    const int h    = n0 / 192;
    const int kind = (n0 % 192) / 64;
    float* dst = (kind == 0) ? Qb : (kind == 1) ? Kb : Vb;
    #pragma unroll
    for (int i = 0; i < 4; ++i) {
        const int t  = m0 + ty + 16*i;
        const int bb = t >> 12;
        const int s  = t & 4095;
        const size_t base = (((size_t)bb * HH + h) * SS + s) * HDIM;
        #pragma unroll
        for (int j = 0; j < 4; ++j) {
            const int d = tx + 16*j;
            dst[base + d] = c[i][j] + bias[n0 + d];
        }
    }
}

// ---------------------------------------------------------------------------
// Kernel 2: QK^T/8 -> write raw logits into attention output region (scratch),
// maintain online row max m and sumexp l over unmasked keys.
// grid (64 q-tiles, 16 bh), 256 threads.
// ---------------------------------------------------------------------------
__global__ __launch_bounds__(256)
void attn_stats(const float* __restrict__ Qb, const float* __restrict__ Kb,
                const int* __restrict__ mask, float* __restrict__ attn,
                float* __restrict__ m_buf, float* __restrict__ l_buf)
{
    __shared__ float Qs[64][68];   // rows 272B (16B aligned), 2-way max
    __shared__ float Ks[64][68];
    const int tid = threadIdx.x;
    const int ty = tid >> 4, tx = tid & 15;
    const int q0 = blockIdx.x * 64;
    const int bh = blockIdx.y;
    const int b  = bh >> 3;
    const float* Qh = Qb + (size_t)bh * SS * HDIM;
    const float* Kh = Kb + (size_t)bh * SS * HDIM;
    float* attn_bh  = attn + (size_t)bh * SS * SS;
    const int* mrow = mask + b * SS;

    #pragma unroll
    for (int rep = 0; rep < 4; ++rep) {
        const int r  = rep * 16 + (tid >> 4);
        const int c4 = (tid & 15) * 4;
        *(float4*)&Qs[r][c4] = *(const float4*)&Qh[(size_t)(q0 + r) * HDIM + c4];
    }

    float m[4], l[4];
    #pragma unroll
    for (int i = 0; i < 4; ++i) { m[i] = -INFINITY; l[i] = 0.f; }

    for (int kt = 0; kt < 64; ++kt) {
        const int k0 = kt * 64;
        #pragma unroll
        for (int rep = 0; rep < 4; ++rep) {
            const int r  = rep * 16 + (tid >> 4);
            const int c4 = (tid & 15) * 4;
            *(float4*)&Ks[r][c4] = *(const float4*)&Kh[(size_t)(k0 + r) * HDIM + c4];
        }
        __syncthreads();

        float c[4][4] = {};
        #pragma unroll
        for (int d0 = 0; d0 < HDIM; d0 += 4) {
            float4 a4[4], b4[4];
            #pragma unroll
            for (int i = 0; i < 4; ++i) a4[i] = *(const float4*)&Qs[ty + 16*i][d0];
            #pragma unroll
            for (int j = 0; j < 4; ++j) b4[j] = *(const float4*)&Ks[tx + 16*j][d0];
            #pragma unroll
            for (int w4 = 0; w4 < 4; ++w4)
                #pragma unroll
                for (int i = 0; i < 4; ++i) {
                    const float av = ((const float*)&a4[i])[w4];
                    #pragma unroll
                    for (int j = 0; j < 4; ++j)
                        c[i][j] = fmaf(av, ((const float*)&b4[j])[w4], c[i][j]);
                }
        }
        #pragma unroll
        for (int i = 0; i < 4; ++i)
            #pragma unroll
            for (int j = 0; j < 4; ++j) c[i][j] *= 0.125f;   // 1/sqrt(64)

        int mk[4];
        #pragma unroll
        for (int j = 0; j < 4; ++j) mk[j] = mrow[k0 + tx + 16*j];

        #pragma unroll
        for (int i = 0; i < 4; ++i) {
            const size_t rowoff = (size_t)(q0 + ty + 16*i) * SS + k0;
            float tm = -INFINITY;
            #pragma unroll
            for (int j = 0; j < 4; ++j) {
                attn_bh[rowoff + tx + 16*j] = c[i][j];     // raw logit scratch
                if (mk[j]) tm = fmaxf(tm, c[i][j]);
            }
            #pragma unroll
            for (int o = 1; o < 16; o <<= 1) tm = fmaxf(tm, __shfl_xor(tm, o));
            const float nm = fmaxf(m[i], tm);
            float s = 0.f;
            #pragma unroll
            for (int j = 0; j < 4; ++j)
                if (mk[j]) s += __expf(c[i][j] - nm);
            #pragma unroll
            for (int o = 1; o < 16; o <<= 1) s += __shfl_xor(s, o);
            const float sc = (m[i] == nm) ? 1.f : __expf(m[i] - nm);
            l[i] = l[i] * sc + s;
            m[i] = nm;
        }
        __syncthreads();
    }

    if (tx == 0) {
        #pragma unroll
        for (int i = 0; i < 4; ++i) {
            const int q = q0 + ty + 16*i;
            m_buf[bh * SS + q] = m[i];
            l_buf[bh * SS + q] = (l[i] > 0.f) ? 1.f / l[i] : 0.f;
        }
    }
}

// ---------------------------------------------------------------------------
// Kernel 3: read logits, p = exp(lg-m)*l^-1 (0 if masked), overwrite attention
// with probs, and accumulate values = P @ V via LDS (P tile x transposed V).
// ---------------------------------------------------------------------------
__global__ __launch_bounds__(256)
void attn_pv(const float* __restrict__ Vb, const int* __restrict__ mask,
             const float* __restrict__ m_buf, const float* __restrict__ l_buf,
             float* __restrict__ attn, float* __restrict__ val)
{
    __shared__ float P[64][68];
    __shared__ float Vt[64][68];   // Vt[d][k]
    const int tid = threadIdx.x;
    const int ty = tid >> 4, tx = tid & 15;
    const int q0 = blockIdx.x * 64;
    const int bh = blockIdx.y;
    const int b  = bh >> 3;
    const float* Vh = Vb + (size_t)bh * SS * HDIM;
    float* attn_bh  = attn + (size_t)bh * SS * SS;
    const int* mrow = mask + b * SS;

    float mr[4], lr[4];
    #pragma unroll
    for (int i = 0; i < 4; ++i) {
        const int q = q0 + ty + 16*i;
        mr[i] = m_buf[bh * SS + q];
        lr[i] = l_buf[bh * SS + q];
    }

    float acc[4][4] = {};

    for (int kt = 0; kt < 64; ++kt) {
        const int k0 = kt * 64;
        #pragma unroll
        for (int rep = 0; rep < 4; ++rep) {        // V tile, transposed into LDS
            const int r  = rep * 16 + (tid >> 4);
            const int c4 = (tid & 15) * 4;
            const float4 v = *(const float4*)&Vh[(size_t)(k0 + r) * HDIM + c4];
            Vt[c4 + 0][r] = v.x;
            Vt[c4 + 1][r] = v.y;
            Vt[c4 + 2][r] = v.z;
            Vt[c4 + 3][r] = v.w;
        }
        int mk[4];
        #pragma unroll
        for (int j = 0; j < 4; ++j) mk[j] = mrow[k0 + tx + 16*j];
        #pragma unroll
        for (int i = 0; i < 4; ++i) {
            const size_t rowoff = (size_t)(q0 + ty + 16*i) * SS + k0;
            #pragma unroll
            for (int j = 0; j < 4; ++j) {
                const float lg = attn_bh[rowoff + tx + 16*j];
                const float p  = mk[j] ? __expf(lg - mr[i]) * lr[i] : 0.f;
                attn_bh[rowoff + tx + 16*j] = p;   // final attention prob
                P[ty + 16*i][tx + 16*j] = p;
            }
        }
        __syncthreads();
        #pragma unroll
        for (int kk0 = 0; kk0 < 64; kk0 += 4) {
            float4 a4[4], b4[4];
            #pragma unroll
            for (int i = 0; i < 4; ++i) a4[i] = *(const float4*)&P[ty + 16*i][kk0];
            #pragma unroll
            for (int j = 0; j < 4; ++j) b4[j] = *(const float4*)&Vt[tx + 16*j][kk0];
            #pragma unroll
            for (int w4 = 0; w4 < 4; ++w4)
                #pragma unroll
                for (int i = 0; i < 4; ++i) {
                    const float av = ((const float*)&a4[i])[w4];
                    #pragma unroll
                    for (int j = 0; j < 4; ++j)
                        acc[i][j] = fmaf(av, ((const float*)&b4[j])[w4], acc[i][j]);
                }
        }
        __syncthreads();
    }

    #pragma unroll
    for (int i = 0; i < 4; ++i) {
        const size_t base = ((size_t)bh * SS + q0 + ty + 16*i) * HDIM;
        #pragma unroll
        for (int j = 0; j < 4; ++j)
            val[base + tx + 16*j] = acc[i][j];
    }
}

// ---------------------------------------------------------------------------
// Kernel 4: o = values @ w_o + b_o.  values read from (B,H,S,64) layout.
// ---------------------------------------------------------------------------
__global__ __launch_bounds__(256)
void oproj_gemm(const float* __restrict__ val, const float* __restrict__ w,
                const float* __restrict__ bias, float* __restrict__ out)
{
    __shared__ float As[64][20];
    __shared__ float Bs[16][64];
    const int tid = threadIdx.x;
    const int ty = tid >> 4, tx = tid & 15;
    const int m0 = blockIdx.x * 64;
    const int n0 = blockIdx.y * 64;

    float c[4][4] = {};

    for (int k0 = 0; k0 < DD; k0 += 16) {
        {
            const int r   = tid >> 2;
            const int c4  = (tid & 3) * 4;
            const int t   = m0 + r;
            const int bb  = t >> 12;
            const int s   = t & 4095;
            const int head = k0 >> 6;          // 16-col window never crosses a head
            const int d    = (k0 & 63) + c4;
            *(float4*)&As[r][c4] =
                *(const float4*)&val[(((size_t)bb * HH + head) * SS + s) * HDIM + d];
            const int br  = tid >> 4;
            const int bc4 = (tid & 15) * 4;
            *(float4*)&Bs[br][bc4] =
                *(const float4*)&w[(size_t)(k0 + br) * DD + n0 + bc4];
        }
        __syncthreads();
        #pragma unroll
        for (int kk0 = 0; kk0 < 16; kk0 += 4) {
            float4 a4[4];
            #pragma unroll
            for (int i = 0; i < 4; ++i) a4[i] = *(const float4*)&As[ty + 16*i][kk0];
            #pragma unroll
            for (int w4 = 0; w4 < 4; ++w4) {
                float bv[4];
                #pragma unroll
                for (int j = 0; j < 4; ++j) bv[j] = Bs[kk0 + w4][tx + 16*j];
                #pragma unroll
                for (int i = 0; i < 4; ++i) {
                    const float av = ((const float*)&a4[i])[w4];
                    #pragma unroll
                    for (int j = 0; j < 4; ++j) c[i][j] = fmaf(av, bv[j], c[i][j]);
                }
            }
        }
        __syncthreads();
    }
    #pragma unroll
    for (int i = 0; i < 4; ++i) {
        const int t = m0 + ty + 16*i;
        #pragma unroll
        for (int j = 0; j < 4; ++j) {
            const int n = n0 + tx + 16*j;
            out[(size_t)t * DD + n] = c[i][j] + bias[n];
        }
    }
}

// ---------------------------------------------------------------------------
extern "C" void kernel_launch(void* const* d_in, const int* in_sizes, int n_in,
                              void* d_out, int out_size, void* d_ws, size_t ws_size,
                              hipStream_t stream)
{
    const float* x     = (const float*)d_in[0];
    const int*   mask  = (const int*)d_in[1];
    const float* w_qkv = (const float*)d_in[2];
    const float* b_qkv = (const float*)d_in[3];
    const float* w_o   = (const float*)d_in[4];
    const float* b_o   = (const float*)d_in[5];

    float* out  = (float*)d_out;
    float* attn = out + (size_t)BB * SS * DD;       // attention region of d_out

    const size_t nqkv = (size_t)BB * HH * SS * HDIM;   // 4,194,304 floats
    float* ws    = (float*)d_ws;                        // needs ~48.5 MB
    float* Qb    = ws;
    float* Kb    = Qb + nqkv;
    float* Vb    = Kb + nqkv;
    float* m_buf = Vb + nqkv;
    float* l_buf = m_buf + (size_t)BB * HH * SS;
    float* val   = Qb;   // Q no longer needed after attn_stats -> reuse

    qkv_gemm  <<<dim3(128, 24), 256, 0, stream>>>(x, w_qkv, b_qkv, Qb, Kb, Vb);
    attn_stats<<<dim3(64, 16),  256, 0, stream>>>(Qb, Kb, mask, attn, m_buf, l_buf);
    attn_pv   <<<dim3(64, 16),  256, 0, stream>>>(Vb, mask, m_buf, l_buf, attn, val);
    oproj_gemm<<<dim3(128, 8),  256, 0, stream>>>(val, w_o, b_o, out);
}

// Round 3
// 1996.222 us; speedup vs baseline: 1.5963x; 1.5963x over previous
//
#include <hip/hip_runtime.h>
#include <math.h>

#define BB   2
#define SS   4096
#define DD   512
#define HH   8
#define HDIM 64

typedef short s16x8 __attribute__((ext_vector_type(8)));   // 8 bf16 = 4 VGPR
typedef float f32x4 __attribute__((ext_vector_type(4)));

__device__ __forceinline__ unsigned short f2bf(float f) {
    union { float f; unsigned int u; } cv; cv.f = f;
    const unsigned int u = cv.u;
    return (unsigned short)((u + 0x7fffu + ((u >> 16) & 1u)) >> 16);  // RNE
}

// ---------------------------------------------------------------------------
// Kernel 1: QKV projection (fp32 math).  x:(B*S,512) @ w_qkv:(512,1536)+b.
// Epilogue writes bf16: Q,K in (B,H,S,64); V transposed (B,H,64,S).
// ---------------------------------------------------------------------------
__global__ __launch_bounds__(256)
void qkv_gemm(const float* __restrict__ x, const float* __restrict__ w,
              const float* __restrict__ bias,
              unsigned short* __restrict__ Qb, unsigned short* __restrict__ Kb,
              unsigned short* __restrict__ Vtb)
{
    __shared__ float As[64][20];
    __shared__ float Bs[16][64];
    const int tid = threadIdx.x;
    const int ty = tid >> 4, tx = tid & 15;
    const int m0 = blockIdx.x * 64;
    const int n0 = blockIdx.y * 64;
    const int N  = 3 * DD;

    float c[4][4] = {};

    for (int k0 = 0; k0 < DD; k0 += 16) {
        {
            const int r  = tid >> 2;
            const int c4 = (tid & 3) * 4;
            *(float4*)&As[r][c4] =
                *(const float4*)&x[(size_t)(m0 + r) * DD + k0 + c4];
            const int br  = tid >> 4;
            const int bc4 = (tid & 15) * 4;
            *(float4*)&Bs[br][bc4] =
                *(const float4*)&w[(size_t)(k0 + br) * N + n0 + bc4];
        }
        __syncthreads();
        #pragma unroll
        for (int kk0 = 0; kk0 < 16; kk0 += 4) {
            float4 a4[4];
            #pragma unroll
            for (int i = 0; i < 4; ++i) a4[i] = *(const float4*)&As[ty + 16*i][kk0];
            #pragma unroll
            for (int w4 = 0; w4 < 4; ++w4) {
                float bv[4];
                #pragma unroll
                for (int j = 0; j < 4; ++j) bv[j] = Bs[kk0 + w4][tx + 16*j];
                #pragma unroll
                for (int i = 0; i < 4; ++i) {
                    const float av = ((const float*)&a4[i])[w4];
                    #pragma unroll
                    for (int j = 0; j < 4; ++j) c[i][j] = fmaf(av, bv[j], c[i][j]);
                }
            }
        }
        __syncthreads();
    }

    const int h    = n0 / 192;          // 192 = 3*64 cols per head
    const int kind = (n0 % 192) / 64;   // 0=Q 1=K 2=V
    #pragma unroll
    for (int i = 0; i < 4; ++i) {
        const int t  = m0 + ty + 16*i;
        const int bb = t >> 12;
        const int s  = t & 4095;
        const int bh = bb * HH + h;
        #pragma unroll
        for (int j = 0; j < 4; ++j) {
            const int d = tx + 16*j;
            const unsigned short bf = f2bf(c[i][j] + bias[n0 + d]);
            if (kind == 2)
                Vtb[((size_t)bh * HDIM + d) * SS + s] = bf;        // V^T
            else if (kind == 1)
                Kb[((size_t)bh * SS + s) * HDIM + d] = bf;
            else
                Qb[((size_t)bh * SS + s) * HDIM + d] = bf;
        }
    }
}

// ---------------------------------------------------------------------------
// Kernel 2: fused attention.  Per block: 64 q-rows x one (b,h).
// 4 waves, each owns a 16-row q-strip.  MFMA 16x16x32 bf16.
// Phase A: QK^T (global->reg frags, no LDS), online masked m/l.
// Phase B: recompute QK^T, p=exp(s-m)/l, write f32 probs (1.07 GB, the only
//          mandatory traffic), P->LDS->A-frag, PV MFMA with V^T frags.
// ---------------------------------------------------------------------------
__global__ __launch_bounds__(256)
void attn_fused(const unsigned short* __restrict__ Qb,
                const unsigned short* __restrict__ Kb,
                const unsigned short* __restrict__ Vtb,
                const int* __restrict__ mask,
                float* __restrict__ attn, float* __restrict__ val)
{
    __shared__ unsigned short Ps[4][16][72];   // per-wave strip, pad->2-way max
    const int tid  = threadIdx.x;
    const int wave = tid >> 6;
    const int lane = tid & 63;
    const int lgrp = lane >> 4;     // 0..3
    const int lcol = lane & 15;     // 0..15
    const int q0   = blockIdx.x * 64;
    const int bh   = blockIdx.y;
    const int b    = bh >> 3;

    const unsigned short* Qh  = Qb  + (size_t)bh * SS * HDIM;
    const unsigned short* Kh  = Kb  + (size_t)bh * SS * HDIM;
    const unsigned short* Vth = Vtb + (size_t)bh * HDIM * SS;
    float* attn_bh = attn + (size_t)bh * SS * SS;
    const int* mrow = mask + b * SS;

    // Q A-frags for this wave's strip: A[m=lcol][k=lgrp*8+j (+32)]
    const int qrow = q0 + wave * 16 + lcol;
    s16x8 qf[2];
    qf[0] = *(const s16x8*)&Qh[(size_t)qrow * HDIM +      lgrp * 8];
    qf[1] = *(const s16x8*)&Qh[(size_t)qrow * HDIM + 32 + lgrp * 8];

    float m_r[4], l_r[4];
    #pragma unroll
    for (int r = 0; r < 4; ++r) { m_r[r] = -INFINITY; l_r[r] = 0.f; }

    // ---------------- phase A: online max / sumexp ----------------
    for (int kt = 0; kt < 64; ++kt) {
        const int k0 = kt * 64;
        s16x8 kf[4][2];
        #pragma unroll
        for (int nk = 0; nk < 4; ++nk) {
            const size_t krow = (size_t)(k0 + nk * 16 + lcol) * HDIM;
            kf[nk][0] = *(const s16x8*)&Kh[krow +      lgrp * 8];
            kf[nk][1] = *(const s16x8*)&Kh[krow + 32 + lgrp * 8];
        }
        float bias[4];
        #pragma unroll
        for (int nk = 0; nk < 4; ++nk)
            bias[nk] = mrow[k0 + nk * 16 + lcol] ? 0.f : -1e9f;

        float sv[4][4];
        #pragma unroll
        for (int nk = 0; nk < 4; ++nk) {
            f32x4 S = {0.f, 0.f, 0.f, 0.f};
            S = __builtin_amdgcn_mfma_f32_16x16x32_bf16(qf[0], kf[nk][0], S, 0, 0, 0);
            S = __builtin_amdgcn_mfma_f32_16x16x32_bf16(qf[1], kf[nk][1], S, 0, 0, 0);
            #pragma unroll
            for (int r = 0; r < 4; ++r) sv[nk][r] = S[r] * 0.125f + bias[nk];
        }
        #pragma unroll
        for (int r = 0; r < 4; ++r) {
            float tm = fmaxf(fmaxf(sv[0][r], sv[1][r]), fmaxf(sv[2][r], sv[3][r]));
            #pragma unroll
            for (int o = 1; o < 16; o <<= 1) tm = fmaxf(tm, __shfl_xor(tm, o));
            const float nm = fmaxf(m_r[r], tm);
            float se = __expf(sv[0][r] - nm) + __expf(sv[1][r] - nm)
                     + __expf(sv[2][r] - nm) + __expf(sv[3][r] - nm);
            #pragma unroll
            for (int o = 1; o < 16; o <<= 1) se += __shfl_xor(se, o);
            l_r[r] = l_r[r] * __expf(m_r[r] - nm) + se;
            m_r[r] = nm;
        }
    }
    float linv[4];
    #pragma unroll
    for (int r = 0; r < 4; ++r) linv[r] = 1.f / l_r[r];

    // ---------------- phase B: probs + PV ----------------
    f32x4 acc[4];
    #pragma unroll
    for (int nd = 0; nd < 4; ++nd) acc[nd] = (f32x4){0.f, 0.f, 0.f, 0.f};

    for (int kt = 0; kt < 64; ++kt) {
        const int k0 = kt * 64;
        s16x8 kf[4][2];
        #pragma unroll
        for (int nk = 0; nk < 4; ++nk) {
            const size_t krow = (size_t)(k0 + nk * 16 + lcol) * HDIM;
            kf[nk][0] = *(const s16x8*)&Kh[krow +      lgrp * 8];
            kf[nk][1] = *(const s16x8*)&Kh[krow + 32 + lgrp * 8];
        }
        float bias[4];
        #pragma unroll
        for (int nk = 0; nk < 4; ++nk)
            bias[nk] = mrow[k0 + nk * 16 + lcol] ? 0.f : -1e9f;

        float p[4][4];
        #pragma unroll
        for (int nk = 0; nk < 4; ++nk) {
            f32x4 S = {0.f, 0.f, 0.f, 0.f};
            S = __builtin_amdgcn_mfma_f32_16x16x32_bf16(qf[0], kf[nk][0], S, 0, 0, 0);
            S = __builtin_amdgcn_mfma_f32_16x16x32_bf16(qf[1], kf[nk][1], S, 0, 0, 0);
            #pragma unroll
            for (int r = 0; r < 4; ++r) {
                const float sv = S[r] * 0.125f + bias[nk];
                p[nk][r] = __expf(sv - m_r[r]) * linv[r];   // bit-identical S -> <=1
                Ps[wave][lgrp * 4 + r][nk * 16 + lcol] = f2bf(p[nk][r]);
            }
        }
        __syncthreads();   // order P writes before A-frag reads (also drains stores)

        // f32 prob store AFTER barrier so the 1.07 GB stream overlaps next compute
        #pragma unroll
        for (int nk = 0; nk < 4; ++nk)
            #pragma unroll
            for (int r = 0; r < 4; ++r)
                attn_bh[(size_t)(q0 + wave * 16 + lgrp * 4 + r) * SS
                        + k0 + nk * 16 + lcol] = p[nk][r];

        s16x8 pa[2];
        pa[0] = *(const s16x8*)&Ps[wave][lcol][     lgrp * 8];
        pa[1] = *(const s16x8*)&Ps[wave][lcol][32 + lgrp * 8];

        s16x8 vf[4][2];
        #pragma unroll
        for (int nd = 0; nd < 4; ++nd) {
            const size_t vrow = (size_t)(nd * 16 + lcol) * SS + k0;
            vf[nd][0] = *(const s16x8*)&Vth[vrow +      lgrp * 8];
            vf[nd][1] = *(const s16x8*)&Vth[vrow + 32 + lgrp * 8];
        }
        #pragma unroll
        for (int nd = 0; nd < 4; ++nd) {
            acc[nd] = __builtin_amdgcn_mfma_f32_16x16x32_bf16(pa[0], vf[nd][0], acc[nd], 0, 0, 0);
            acc[nd] = __builtin_amdgcn_mfma_f32_16x16x32_bf16(pa[1], vf[nd][1], acc[nd], 0, 0, 0);
        }
    }

    // epilogue: values (f32) in (B,H,S,64)
    #pragma unroll
    for (int nd = 0; nd < 4; ++nd)
        #pragma unroll
        for (int r = 0; r < 4; ++r)
            val[((size_t)bh * SS + q0 + wave * 16 + lgrp * 4 + r) * HDIM
                + nd * 16 + lcol] = acc[nd][r];
}

// ---------------------------------------------------------------------------
// Kernel 3: o = values @ w_o + b_o   (fp32, values read from (B,H,S,64))
// ---------------------------------------------------------------------------
__global__ __launch_bounds__(256)
void oproj_gemm(const float* __restrict__ val, const float* __restrict__ w,
                const float* __restrict__ bias, float* __restrict__ out)
{
    __shared__ float As[64][20];
    __shared__ float Bs[16][64];
    const int tid = threadIdx.x;
    const int ty = tid >> 4, tx = tid & 15;
    const int m0 = blockIdx.x * 64;
    const int n0 = blockIdx.y * 64;

    float c[4][4] = {};

    for (int k0 = 0; k0 < DD; k0 += 16) {
        {
            const int r   = tid >> 2;
            const int c4  = (tid & 3) * 4;
            const int t   = m0 + r;
            const int bb  = t >> 12;
            const int s   = t & 4095;
            const int head = k0 >> 6;
            const int d    = (k0 & 63) + c4;
            *(float4*)&As[r][c4] =
                *(const float4*)&val[(((size_t)bb * HH + head) * SS + s) * HDIM + d];
            const int br  = tid >> 4;
            const int bc4 = (tid & 15) * 4;
            *(float4*)&Bs[br][bc4] =
                *(const float4*)&w[(size_t)(k0 + br) * DD + n0 + bc4];
        }
        __syncthreads();
        #pragma unroll
        for (int kk0 = 0; kk0 < 16; kk0 += 4) {
            float4 a4[4];
            #pragma unroll
            for (int i = 0; i < 4; ++i) a4[i] = *(const float4*)&As[ty + 16*i][kk0];
            #pragma unroll
            for (int w4 = 0; w4 < 4; ++w4) {
                float bv[4];
                #pragma unroll
                for (int j = 0; j < 4; ++j) bv[j] = Bs[kk0 + w4][tx + 16*j];
                #pragma unroll
                for (int i = 0; i < 4; ++i) {
                    const float av = ((const float*)&a4[i])[w4];
                    #pragma unroll
                    for (int j = 0; j < 4; ++j) c[i][j] = fmaf(av, bv[j], c[i][j]);
                }
            }
        }
        __syncthreads();
    }
    #pragma unroll
    for (int i = 0; i < 4; ++i) {
        const int t = m0 + ty + 16*i;
        #pragma unroll
        for (int j = 0; j < 4; ++j) {
            const int n = n0 + tx + 16*j;
            out[(size_t)t * DD + n] = c[i][j] + bias[n];
        }
    }
}

// ---------------------------------------------------------------------------
extern "C" void kernel_launch(void* const* d_in, const int* in_sizes, int n_in,
                              void* d_out, int out_size, void* d_ws, size_t ws_size,
                              hipStream_t stream)
{
    const float* x     = (const float*)d_in[0];
    const int*   mask  = (const int*)d_in[1];
    const float* w_qkv = (const float*)d_in[2];
    const float* b_qkv = (const float*)d_in[3];
    const float* w_o   = (const float*)d_in[4];
    const float* b_o   = (const float*)d_in[5];

    float* out  = (float*)d_out;
    float* attn = out + (size_t)BB * SS * DD;

    const size_t nqkv = (size_t)BB * HH * SS * HDIM;   // 4,194,304
    unsigned short* Qb  = (unsigned short*)d_ws;        // 8.4 MB each
    unsigned short* Kb  = Qb + nqkv;
    unsigned short* Vtb = Kb + nqkv;
    float*          val = (float*)(Vtb + nqkv);         // 16.8 MB

    qkv_gemm  <<<dim3(128, 24), 256, 0, stream>>>(x, w_qkv, b_qkv, Qb, Kb, Vtb);
    attn_fused<<<dim3(64, 16),  256, 0, stream>>>(Qb, Kb, Vtb, mask, attn, val);
    oproj_gemm<<<dim3(128, 8),  256, 0, stream>>>(val, w_o, b_o, out);
}